// Round 2
// baseline (238.476 us; speedup 1.0000x reference)
//
#include <hip/hip_runtime.h>
#include <stdint.h>

#define VCH 4   // vote-axis split factor

// Spread 8 bits of a byte into 8 byte-lanes of a uint64.
// Lane k (byte k) gets bit (7-k) of b, as 0 or 1.
__device__ __forceinline__ uint64_t spread8(uint32_t b) {
    return (((uint64_t)b * 0x8040201008040201ULL) >> 7) & 0x0101010101010101ULL;
}

// Sum of the 8 byte lanes (valid while sum < 256).
__device__ __forceinline__ uint32_t bytesum(uint64_t c) {
    return (uint32_t)((c * 0x0101010101010101ULL) >> 56);
}

// Kernel 1: per byte-position bit counts over a chunk of the vote axis.
// Thread owns 4 consecutive byte positions; blockIdx.y picks the vote chunk.
// Partial counts merged into cnt via uint64 atomics (byte lanes ≤ 32, no
// cross-lane carry possible).
__global__ __launch_bounds__(256) void k_count(const int* __restrict__ flip,
                                               uint64_t* __restrict__ cnt,
                                               unsigned int* __restrict__ total,
                                               int npos, int nvotes) {
    int t = blockIdx.x * blockDim.x + threadIdx.x;   // position-group id
    int base = t * 4;
    if (base >= npos) return;
    int c  = blockIdx.y;
    int cs = nvotes / VCH;
    int v0 = c * cs;
    int v1 = (c == VCH - 1) ? nvotes : v0 + cs;
    const int4* fp = (const int4*)flip;
    int stride = npos >> 2;                          // int4 stride between votes
    uint64_t c0 = 0, c1 = 0, c2 = 0, c3 = 0;
#pragma unroll 4
    for (int v = v0; v < v1; ++v) {
        int4 x = fp[(size_t)v * stride + t];
        c0 += spread8((uint32_t)x.x & 0xFFu);
        c1 += spread8((uint32_t)x.y & 0xFFu);
        c2 += spread8((uint32_t)x.z & 0xFFu);
        c3 += spread8((uint32_t)x.w & 0xFFu);
    }
    atomicAdd((unsigned long long*)(cnt + base + 0), (unsigned long long)c0);
    atomicAdd((unsigned long long*)(cnt + base + 1), (unsigned long long)c1);
    atomicAdd((unsigned long long*)(cnt + base + 2), (unsigned long long)c2);
    atomicAdd((unsigned long long*)(cnt + base + 3), (unsigned long long)c3);
    // popcount of this chunk's bits = sum of byte lanes (each bytesum ≤ 64)
    unsigned int pop = bytesum(c0) + bytesum(c1) + bytesum(c2) + bytesum(c3);
    for (int off = 32; off > 0; off >>= 1)
        pop += __shfl_down(pop, off, 64);
    if ((threadIdx.x & 63) == 0)
        atomicAdd(total, pop);
}

// Kernel 2: threshold, build mask, XNOR with weights, write floats, count mask
// bits; last block writes the update ratio (fused former k_ratio).
__global__ __launch_bounds__(256) void k_apply(const int* __restrict__ weights,
                                               const uint64_t* __restrict__ cnt,
                                               const unsigned int* __restrict__ total,
                                               const float* __restrict__ vote_p_max,
                                               const int* __restrict__ n_votes_p,
                                               float* __restrict__ out,
                                               unsigned int* __restrict__ maskpop,
                                               unsigned int* __restrict__ done,
                                               int npos) {
    int t = blockIdx.x * blockDim.x + threadIdx.x;
    int base = t * 4;
    bool active = (base < npos);
    if (active) {
        float nv = (float)n_votes_p[0];
        float mean = (float)((double)(*total) / ((double)npos * 8.0));
        float thresh = fmaxf(vote_p_max[0] * nv, mean);  // == max(p,mean/nv)*nv
        const ulonglong2* cp = (const ulonglong2*)(cnt + base);
        ulonglong2 a = cp[0], b = cp[1];
        uint64_t cs[4] = {a.x, a.y, b.x, b.y};
        int4 w = ((const int4*)weights)[t];
        int wv[4] = {w.x, w.y, w.z, w.w};
        float o[4];
        unsigned int pop = 0;
#pragma unroll
        for (int j = 0; j < 4; ++j) {
            uint32_t mask = 0;
            uint64_t cc = cs[j];
#pragma unroll
            for (int k = 0; k < 8; ++k) {
                uint32_t lane = (uint32_t)(cc >> (8 * k)) & 0xFFu;  // count of bit 7-k
                if ((float)lane > thresh) mask |= 1u << (7 - k);
            }
            pop += __popc(mask);
            o[j] = (float)((~(((uint32_t)wv[j]) ^ mask)) & 0xFFu);
        }
        ((float4*)out)[t] = make_float4(o[0], o[1], o[2], o[3]);
        for (int off = 32; off > 0; off >>= 1)
            pop += __shfl_down(pop, off, 64);
        if ((threadIdx.x & 63) == 0)
            atomicAdd(maskpop, pop);
    }
    __syncthreads();
    __shared__ bool last;
    if (threadIdx.x == 0) {
        __threadfence();
        unsigned int prev = atomicAdd(done, 1);
        last = (prev == gridDim.x - 1);
    }
    __syncthreads();
    if (last && threadIdx.x == 0) {
        unsigned int mp = atomicAdd(maskpop, 0u);    // coherent read after all adds
        out[npos] = (float)((double)mp / ((double)npos * 8.0));
    }
}

extern "C" void kernel_launch(void* const* d_in, const int* in_sizes, int n_in,
                              void* d_out, int out_size, void* d_ws, size_t ws_size,
                              hipStream_t stream) {
    const int* weights      = (const int*)d_in[0];   // 2048*256 bytes, one per int32
    const int* flip         = (const int*)d_in[1];   // 32*2048*256, one byte per int32
    const int* n_votes_p    = (const int*)d_in[2];
    const float* vote_p_max = (const float*)d_in[3];

    int npos   = in_sizes[0];               // 524288 byte positions
    int nvotes = in_sizes[1] / in_sizes[0]; // 32

    // ws layout: [0..256) counters (total, maskpop, done); [256..256+8*npos) counts
    unsigned int* counters = (unsigned int*)d_ws;
    uint64_t* cnt = (uint64_t*)((char*)d_ws + 256);
    hipMemsetAsync(d_ws, 0, 256 + (size_t)npos * 8, stream);  // zero counters + cnt

    int nthreads = npos / 4;                // 131072
    int block = 256;
    int gx = (nthreads + block - 1) / block;  // 512

    dim3 gridc(gx, VCH);
    k_count<<<gridc, block, 0, stream>>>(flip, cnt, counters, npos, nvotes);
    k_apply<<<gx, block, 0, stream>>>(weights, cnt, counters, vote_p_max,
                                      n_votes_p, (float*)d_out, counters + 1,
                                      counters + 2, npos);
}